// Round 3
// baseline (624.316 us; speedup 1.0000x reference)
//
#include <hip/hip_runtime.h>

// SparseToDense: scatter [N, C] f32 features at flat (b,z,y,x) indices into
// dense [B, C, S, S, S] f32 output (channels-first).
// Fixed shape: N=262144, C=64, S=64, B=8. S^3=2^18, NCELL=2^21, out=512 MiB.
//
// Inverted-scatter structure:
//   Phase 1: head[cell] = -1                       (8 MiB in d_ws)
//   Phase 2: linked lists: nxt[n] = atomicExch(&head[idx[n]], n)
//   Phase 3: register-tile emit. One thread = 4 consecutive cells x 64 ch,
//     processed as 4 chunks of 16 channels entirely in registers:
//       - head int4 read once (coalesced)
//       - per chunk: zero acc[64]; walk each cell's (short) list, load the
//         site row's 64 B chunk as 4x dwordx4 (exactly one cache line);
//       - store 16 channels: in-register transpose -> ONE nontemporal
//         global_store_dwordx4 per channel, consecutive lanes consecutive
//         16 B -> full-line coalesced streaming writes. No LDS, no barriers.
//   => feat read once (64 MiB), head once (8 MiB), out written once
//      (512 MiB full-line). ~590 MiB total HBM traffic.

#define C_CH      64
#define LOG_C     6
#define LOG_S3    18
#define S3        (1 << LOG_S3)           // 262144 cells per batch
#define NCELL     (8 * S3)                // 2,097,152
#define OUT_ELEMS (8LL * C_CH * S3)       // 134,217,728 floats

typedef float v4f __attribute__((ext_vector_type(4)));

__global__ void init_head_kernel(int* __restrict__ head) {
    int i = blockIdx.x * blockDim.x + threadIdx.x;   // NCELL/4 threads
    ((int4*)head)[i] = make_int4(-1, -1, -1, -1);
}

__global__ void build_lists_kernel(const int* __restrict__ idx,
                                   int* __restrict__ head,
                                   int* __restrict__ nxt, int n) {
    int i = blockIdx.x * blockDim.x + threadIdx.x;
    if (i < n) {
        int cell = idx[i];
        nxt[i] = atomicExch(&head[cell], i);
    }
}

// grid: NCELL / 1024 = 2048 blocks of 256 threads; thread owns 4 cells.
__global__ void __launch_bounds__(256)
emit_reg_kernel(const float* __restrict__ feat,
                const int* __restrict__ head,
                const int* __restrict__ nxt,
                float* __restrict__ out) {
    const int b      = blockIdx.x >> 8;              // 256 blocks per batch
    const int s_base = (blockIdx.x & 255) << 10;     // 1024 cells per block
    const int cell0  = s_base + (threadIdx.x << 2);  // this thread's 4 cells

    const int4 h4 = *(const int4*)(head + ((size_t)b << LOG_S3) + cell0);
    int hs[4] = {h4.x, h4.y, h4.z, h4.w};

    #pragma unroll 1
    for (int chunk = 0; chunk < 4; ++chunk) {
        float acc[64];                               // [cell j][channel cc]
        #pragma unroll
        for (int i = 0; i < 64; ++i) acc[i] = 0.f;

        #pragma unroll
        for (int j = 0; j < 4; ++j) {
            int p = hs[j];
            while (p >= 0) {
                const v4f* fr = (const v4f*)(feat + ((size_t)p << LOG_C)
                                             + (chunk << 4));
                v4f f0 = fr[0], f1 = fr[1], f2 = fr[2], f3 = fr[3];
                float* a = acc + j * 16;
                a[0]  += f0.x; a[1]  += f0.y; a[2]  += f0.z; a[3]  += f0.w;
                a[4]  += f1.x; a[5]  += f1.y; a[6]  += f1.z; a[7]  += f1.w;
                a[8]  += f2.x; a[9]  += f2.y; a[10] += f2.z; a[11] += f2.w;
                a[12] += f3.x; a[13] += f3.y; a[14] += f3.z; a[15] += f3.w;
                p = nxt[p];
            }
        }

        // channel c = chunk*16 + cc ; out[((b*64+c)<<18) + cell0 .. +3]
        const size_t obase = ((size_t)((b << LOG_C) + (chunk << 4)) << LOG_S3)
                             + cell0;
        #pragma unroll
        for (int cc = 0; cc < 16; ++cc) {
            v4f v = {acc[cc], acc[16 + cc], acc[32 + cc], acc[48 + cc]};
            __builtin_nontemporal_store(
                v, (v4f*)(out + obase + ((size_t)cc << LOG_S3)));
        }
    }
}

// ---------------- fallback path (only if d_ws were too small) ----------------
__global__ void zero_out_kernel(float4* __restrict__ out) {
    long long i = (long long)blockIdx.x * blockDim.x + threadIdx.x;
    out[i] = make_float4(0.f, 0.f, 0.f, 0.f);
}

__global__ void scatter_atomic_kernel(const float* __restrict__ feat,
                                      const int* __restrict__ idx,
                                      float* __restrict__ out, int n) {
    int i = blockIdx.x * blockDim.x + threadIdx.x;
    int nn = i >> LOG_C;
    int c  = i & (C_CH - 1);
    if (nn < n) {
        int cell = idx[nn];
        int b = cell >> LOG_S3;
        int s = cell & (S3 - 1);
        long long o = (((long long)((b << LOG_C) + c)) << LOG_S3) + s;
        atomicAdd(&out[o], feat[i]);
    }
}

extern "C" void kernel_launch(void* const* d_in, const int* in_sizes, int n_in,
                              void* d_out, int out_size, void* d_ws, size_t ws_size,
                              hipStream_t stream) {
    const float* feat = (const float*)d_in[0];
    const int*   idx  = (const int*)d_in[1];
    float*       out  = (float*)d_out;
    const int N = in_sizes[1];                       // 262144 active sites

    const size_t head_bytes = (size_t)NCELL * sizeof(int);   // 8 MiB
    const size_t next_bytes = (size_t)N * sizeof(int);       // 1 MiB

    if (ws_size >= head_bytes + next_bytes) {
        int* head = (int*)d_ws;
        int* nxt  = (int*)((char*)d_ws + head_bytes);

        init_head_kernel<<<NCELL / 4 / 256, 256, 0, stream>>>(head);
        build_lists_kernel<<<(N + 255) / 256, 256, 0, stream>>>(idx, head, nxt, N);
        emit_reg_kernel<<<NCELL / 1024, 256, 0, stream>>>(feat, head, nxt, out);
    } else {
        zero_out_kernel<<<(int)(OUT_ELEMS / 4 / 256), 256, 0, stream>>>((float4*)out);
        scatter_atomic_kernel<<<(N * C_CH) / 256, 256, 0, stream>>>(feat, idx, out, N);
    }
}